// Round 1
// baseline (132.946 us; speedup 1.0000x reference)
//
#include <hip/hip_runtime.h>
#include <math.h>

namespace {
constexpr int Bn = 16;
constexpr int Sn = 256;
constexpr int Dn = 256;
constexpr float EPS_ATTN = 1e-6f;
constexpr float EPS_BN = 1e-5f;
constexpr int OUT2 = Bn * 2 * Sn * Dn;  // float offset of second output tensor

// ---------------------------------------------------------------------------
// K1: attn[b, j, i] = 1 / (1 + sqrt(||x1[b,i,:] - x2[b,j,:]||^2 + EPS_ATTN))
// via dist2 = ||a||^2 + ||b||^2 - 2 a.b ; 64x64 tile per block, 4x4 per thread
// LDS layout [d][row] so fragment reads are aligned float4.
// ---------------------------------------------------------------------------
__global__ __launch_bounds__(256) void k1_attn(const float* __restrict__ x1,
                                               const float* __restrict__ x2,
                                               float* __restrict__ attn) {
  __shared__ __align__(16) float a_s[2][32][64];  // [buf][d][i]
  __shared__ __align__(16) float b_s[2][32][64];  // [buf][d][j]
  const int b = blockIdx.z;
  const int ibase = blockIdx.x * 64;
  const int jbase = blockIdx.y * 64;
  const int t = threadIdx.x;
  const int i0 = (t & 15) * 4;
  const int j0 = (t >> 4) * 4;
  const float* x1b = x1 + (b * Sn + ibase) * Dn;
  const float* x2b = x2 + (b * Sn + jbase) * Dn;

  // staging: 512 float4 per tile-chunk (64 rows x 32 d), 2 per thread
  const int p0 = 2 * t, p1 = 2 * t + 1;
  const int r0 = p0 >> 3, c0 = (p0 & 7) * 4;
  const int r1 = p1 >> 3, c1 = (p1 & 7) * 4;

  float4 pa0 = *(const float4*)(x1b + r0 * Dn + c0);
  float4 pa1 = *(const float4*)(x1b + r1 * Dn + c1);
  float4 pb0 = *(const float4*)(x2b + r0 * Dn + c0);
  float4 pb1 = *(const float4*)(x2b + r1 * Dn + c1);

  float dot[4][4];  // [jj][ii]
#pragma unroll
  for (int a = 0; a < 4; ++a)
#pragma unroll
    for (int c = 0; c < 4; ++c) dot[a][c] = 0.f;
  float na[4] = {0.f, 0.f, 0.f, 0.f};
  float nb[4] = {0.f, 0.f, 0.f, 0.f};

  // write chunk 0
  a_s[0][c0 + 0][r0] = pa0.x; a_s[0][c0 + 1][r0] = pa0.y;
  a_s[0][c0 + 2][r0] = pa0.z; a_s[0][c0 + 3][r0] = pa0.w;
  a_s[0][c1 + 0][r1] = pa1.x; a_s[0][c1 + 1][r1] = pa1.y;
  a_s[0][c1 + 2][r1] = pa1.z; a_s[0][c1 + 3][r1] = pa1.w;
  b_s[0][c0 + 0][r0] = pb0.x; b_s[0][c0 + 1][r0] = pb0.y;
  b_s[0][c0 + 2][r0] = pb0.z; b_s[0][c0 + 3][r0] = pb0.w;
  b_s[0][c1 + 0][r1] = pb1.x; b_s[0][c1 + 1][r1] = pb1.y;
  b_s[0][c1 + 2][r1] = pb1.z; b_s[0][c1 + 3][r1] = pb1.w;
  __syncthreads();

  int buf = 0;
  for (int kc = 0; kc < 8; ++kc) {
    if (kc < 7) {
      const int d0 = (kc + 1) * 32;
      pa0 = *(const float4*)(x1b + r0 * Dn + d0 + c0);
      pa1 = *(const float4*)(x1b + r1 * Dn + d0 + c1);
      pb0 = *(const float4*)(x2b + r0 * Dn + d0 + c0);
      pb1 = *(const float4*)(x2b + r1 * Dn + d0 + c1);
    }
#pragma unroll
    for (int d = 0; d < 32; ++d) {
      const float4 av = *(const float4*)&a_s[buf][d][i0];
      const float4 bv = *(const float4*)&b_s[buf][d][j0];
      na[0] = fmaf(av.x, av.x, na[0]);
      na[1] = fmaf(av.y, av.y, na[1]);
      na[2] = fmaf(av.z, av.z, na[2]);
      na[3] = fmaf(av.w, av.w, na[3]);
      nb[0] = fmaf(bv.x, bv.x, nb[0]);
      nb[1] = fmaf(bv.y, bv.y, nb[1]);
      nb[2] = fmaf(bv.z, bv.z, nb[2]);
      nb[3] = fmaf(bv.w, bv.w, nb[3]);
      dot[0][0] = fmaf(av.x, bv.x, dot[0][0]);
      dot[0][1] = fmaf(av.y, bv.x, dot[0][1]);
      dot[0][2] = fmaf(av.z, bv.x, dot[0][2]);
      dot[0][3] = fmaf(av.w, bv.x, dot[0][3]);
      dot[1][0] = fmaf(av.x, bv.y, dot[1][0]);
      dot[1][1] = fmaf(av.y, bv.y, dot[1][1]);
      dot[1][2] = fmaf(av.z, bv.y, dot[1][2]);
      dot[1][3] = fmaf(av.w, bv.y, dot[1][3]);
      dot[2][0] = fmaf(av.x, bv.z, dot[2][0]);
      dot[2][1] = fmaf(av.y, bv.z, dot[2][1]);
      dot[2][2] = fmaf(av.z, bv.z, dot[2][2]);
      dot[2][3] = fmaf(av.w, bv.z, dot[2][3]);
      dot[3][0] = fmaf(av.x, bv.w, dot[3][0]);
      dot[3][1] = fmaf(av.y, bv.w, dot[3][1]);
      dot[3][2] = fmaf(av.z, bv.w, dot[3][2]);
      dot[3][3] = fmaf(av.w, bv.w, dot[3][3]);
    }
    if (kc < 7) {
      const int nbuf = buf ^ 1;
      a_s[nbuf][c0 + 0][r0] = pa0.x; a_s[nbuf][c0 + 1][r0] = pa0.y;
      a_s[nbuf][c0 + 2][r0] = pa0.z; a_s[nbuf][c0 + 3][r0] = pa0.w;
      a_s[nbuf][c1 + 0][r1] = pa1.x; a_s[nbuf][c1 + 1][r1] = pa1.y;
      a_s[nbuf][c1 + 2][r1] = pa1.z; a_s[nbuf][c1 + 3][r1] = pa1.w;
      b_s[nbuf][c0 + 0][r0] = pb0.x; b_s[nbuf][c0 + 1][r0] = pb0.y;
      b_s[nbuf][c0 + 2][r0] = pb0.z; b_s[nbuf][c0 + 3][r0] = pb0.w;
      b_s[nbuf][c1 + 0][r1] = pb1.x; b_s[nbuf][c1 + 1][r1] = pb1.y;
      b_s[nbuf][c1 + 2][r1] = pb1.z; b_s[nbuf][c1 + 3][r1] = pb1.w;
    }
    __syncthreads();
    buf ^= 1;
  }

#pragma unroll
  for (int jj = 0; jj < 4; ++jj) {
    const int j = jbase + j0 + jj;
    float4 o;
    o.x = 1.f / (sqrtf(fmaxf(na[0] + nb[jj] - 2.f * dot[jj][0], 0.f) + EPS_ATTN) + 1.f);
    o.y = 1.f / (sqrtf(fmaxf(na[1] + nb[jj] - 2.f * dot[jj][1], 0.f) + EPS_ATTN) + 1.f);
    o.z = 1.f / (sqrtf(fmaxf(na[2] + nb[jj] - 2.f * dot[jj][2], 0.f) + EPS_ATTN) + 1.f);
    o.w = 1.f / (sqrtf(fmaxf(na[3] + nb[jj] - 2.f * dot[jj][3], 0.f) + EPS_ATTN) + 1.f);
    *(float4*)(attn + (b * Sn + j) * Sn + ibase + i0) = o;
  }
}

// ---------------------------------------------------------------------------
// K2: which=0: C(i,o) = sum_j attn[b,j,i] * W[o,j] + bias  -> out1 ch1 plane
//     which=1: C(j,o) = sum_i attn[b,j,i] * W[o,i] + bias  -> out2 ch1 plane
// Writes directly into d_out channel-1 slots (K4 normalizes in place).
// ---------------------------------------------------------------------------
__global__ __launch_bounds__(256) void k2_gemm(const float* __restrict__ attn,
                                               const float* __restrict__ Wp,
                                               const float* __restrict__ bias,
                                               float* __restrict__ out) {
  __shared__ __align__(16) float a_s[2][32][64];  // [buf][k][m]
  __shared__ __align__(16) float w_s[2][32][64];  // [buf][k][o]
  const int z = blockIdx.z;
  const int b = z >> 1;
  const int which = z & 1;
  const int mbase = blockIdx.x * 64;
  const int obase = blockIdx.y * 64;
  const int t = threadIdx.x;
  const int m0 = (t & 15) * 4;
  const int o0 = (t >> 4) * 4;
  const float* A = attn + b * Sn * Sn;

  const int p0 = 2 * t, p1 = 2 * t + 1;
  // transposed staging pattern (W always; A when which==1)
  const int to0 = p0 >> 3, tk0 = (p0 & 7) * 4;
  const int to1 = p1 >> 3, tk1 = (p1 & 7) * 4;
  // direct staging pattern (A when which==0)
  const int ak0 = p0 >> 4, am0 = (p0 & 15) * 4;
  const int ak1 = p1 >> 4, am1 = (p1 & 15) * 4;

  float4 va0, va1, vw0, vw1;
  auto load_chunk = [&](int k0) {
    if (which == 0) {
      va0 = *(const float4*)(A + (k0 + ak0) * Sn + mbase + am0);
      va1 = *(const float4*)(A + (k0 + ak1) * Sn + mbase + am1);
    } else {
      va0 = *(const float4*)(A + (mbase + to0) * Sn + k0 + tk0);
      va1 = *(const float4*)(A + (mbase + to1) * Sn + k0 + tk1);
    }
    vw0 = *(const float4*)(Wp + (obase + to0) * Sn + k0 + tk0);
    vw1 = *(const float4*)(Wp + (obase + to1) * Sn + k0 + tk1);
  };
  auto store_chunk = [&](int bf) {
    if (which == 0) {
      *(float4*)&a_s[bf][ak0][am0] = va0;
      *(float4*)&a_s[bf][ak1][am1] = va1;
    } else {
      a_s[bf][tk0 + 0][to0] = va0.x; a_s[bf][tk0 + 1][to0] = va0.y;
      a_s[bf][tk0 + 2][to0] = va0.z; a_s[bf][tk0 + 3][to0] = va0.w;
      a_s[bf][tk1 + 0][to1] = va1.x; a_s[bf][tk1 + 1][to1] = va1.y;
      a_s[bf][tk1 + 2][to1] = va1.z; a_s[bf][tk1 + 3][to1] = va1.w;
    }
    w_s[bf][tk0 + 0][to0] = vw0.x; w_s[bf][tk0 + 1][to0] = vw0.y;
    w_s[bf][tk0 + 2][to0] = vw0.z; w_s[bf][tk0 + 3][to0] = vw0.w;
    w_s[bf][tk1 + 0][to1] = vw1.x; w_s[bf][tk1 + 1][to1] = vw1.y;
    w_s[bf][tk1 + 2][to1] = vw1.z; w_s[bf][tk1 + 3][to1] = vw1.w;
  };

  float acc[4][4];  // [mm][oo]
#pragma unroll
  for (int a = 0; a < 4; ++a)
#pragma unroll
    for (int c = 0; c < 4; ++c) acc[a][c] = 0.f;

  load_chunk(0);
  store_chunk(0);
  __syncthreads();

  int buf = 0;
  for (int kc = 0; kc < 8; ++kc) {
    if (kc < 7) load_chunk((kc + 1) * 32);
#pragma unroll
    for (int d = 0; d < 32; ++d) {
      const float4 av = *(const float4*)&a_s[buf][d][m0];
      const float4 wv = *(const float4*)&w_s[buf][d][o0];
      acc[0][0] = fmaf(av.x, wv.x, acc[0][0]);
      acc[0][1] = fmaf(av.x, wv.y, acc[0][1]);
      acc[0][2] = fmaf(av.x, wv.z, acc[0][2]);
      acc[0][3] = fmaf(av.x, wv.w, acc[0][3]);
      acc[1][0] = fmaf(av.y, wv.x, acc[1][0]);
      acc[1][1] = fmaf(av.y, wv.y, acc[1][1]);
      acc[1][2] = fmaf(av.y, wv.z, acc[1][2]);
      acc[1][3] = fmaf(av.y, wv.w, acc[1][3]);
      acc[2][0] = fmaf(av.z, wv.x, acc[2][0]);
      acc[2][1] = fmaf(av.z, wv.y, acc[2][1]);
      acc[2][2] = fmaf(av.z, wv.z, acc[2][2]);
      acc[2][3] = fmaf(av.z, wv.w, acc[2][3]);
      acc[3][0] = fmaf(av.w, wv.x, acc[3][0]);
      acc[3][1] = fmaf(av.w, wv.y, acc[3][1]);
      acc[3][2] = fmaf(av.w, wv.z, acc[3][2]);
      acc[3][3] = fmaf(av.w, wv.w, acc[3][3]);
    }
    if (kc < 7) store_chunk(buf ^ 1);
    __syncthreads();
    buf ^= 1;
  }

  const float4 bsv = *(const float4*)(bias + obase + o0);
  float* dst = out + (which ? OUT2 : 0) + ((2 * b + 1) * Sn + mbase) * Dn + obase;
#pragma unroll
  for (int mm = 0; mm < 4; ++mm) {
    float4 o;
    o.x = acc[mm][0] + bsv.x;
    o.y = acc[mm][1] + bsv.y;
    o.z = acc[mm][2] + bsv.z;
    o.w = acc[mm][3] + bsv.w;
    *(float4*)(dst + (m0 + mm) * Dn + o0) = o;
  }
}

// ---------------------------------------------------------------------------
// K3a: per-block partial sum/sumsq for 4 channels (x1, x1_att, x2, x2_att)
// ---------------------------------------------------------------------------
__global__ __launch_bounds__(256) void k3a_partial(const float* __restrict__ x1,
                                                   const float* __restrict__ x2,
                                                   const float* __restrict__ out,
                                                   float* __restrict__ psum,
                                                   float* __restrict__ psq) {
  const int ch = blockIdx.y;
  const int t = threadIdx.x;
  const int base4 = blockIdx.x * 1024;
  float s = 0.f, q = 0.f;
#pragma unroll
  for (int u = 0; u < 4; ++u) {
    const int idx = base4 + u * 256 + t;  // f4 index within channel
    float4 v;
    if (ch == 0) {
      v = ((const float4*)x1)[idx];
    } else if (ch == 2) {
      v = ((const float4*)x2)[idx];
    } else {
      const int bb = idx >> 14, r = idx & 16383;
      const int off = ((ch == 1) ? 0 : (OUT2 / 4)) + bb * 32768 + 16384 + r;
      v = ((const float4*)out)[off];
    }
    s += v.x + v.y + v.z + v.w;
    q += v.x * v.x + v.y * v.y + v.z * v.z + v.w * v.w;
  }
  for (int off = 32; off; off >>= 1) {
    s += __shfl_down(s, off);
    q += __shfl_down(q, off);
  }
  __shared__ float ls[4], lq[4];
  if ((t & 63) == 0) { ls[t >> 6] = s; lq[t >> 6] = q; }
  __syncthreads();
  if (t == 0) {
    psum[ch * 256 + blockIdx.x] = ls[0] + ls[1] + ls[2] + ls[3];
    psq[ch * 256 + blockIdx.x] = lq[0] + lq[1] + lq[2] + lq[3];
  }
}

// ---------------------------------------------------------------------------
// K3b: finalize mean / inv_std per channel (one wave per channel)
// ---------------------------------------------------------------------------
__global__ __launch_bounds__(256) void k3b_final(const float* __restrict__ psum,
                                                 const float* __restrict__ psq,
                                                 float* __restrict__ stats) {
  const int t = threadIdx.x;
  const int ch = t >> 6;
  const int l = t & 63;
  float s = 0.f, q = 0.f;
#pragma unroll
  for (int u = 0; u < 4; ++u) {
    s += psum[ch * 256 + u * 64 + l];
    q += psq[ch * 256 + u * 64 + l];
  }
  for (int off = 32; off; off >>= 1) {
    s += __shfl_down(s, off);
    q += __shfl_down(q, off);
  }
  if (l == 0) {
    const float n = (float)(Bn * Sn * Dn);
    const float mean = s / n;
    const float var = q / n - mean * mean;
    stats[ch * 2 + 0] = mean;
    stats[ch * 2 + 1] = rsqrtf(var + EPS_BN);
  }
}

// ---------------------------------------------------------------------------
// K4: normalize; channel 0 planes copied from x1/x2, channel 1 planes in-place
// ---------------------------------------------------------------------------
__global__ __launch_bounds__(256) void k4_bn(const float* __restrict__ x1,
                                             const float* __restrict__ x2,
                                             const float* __restrict__ stats,
                                             const float* __restrict__ gamma,
                                             const float* __restrict__ beta,
                                             float* __restrict__ out) {
  const int idx4 = blockIdx.x * 256 + threadIdx.x;  // 0 .. 1048575 (f4 units)
  const int tensor = idx4 >> 19;
  const int rem = idx4 & 524287;
  const int bb = rem >> 15;
  const int rem2 = rem & 32767;
  const int c = rem2 >> 14;
  const int r4 = rem2 & 16383;
  const int ch = tensor * 2 + c;
  float4 v;
  if (c == 0) {
    const float* src = tensor ? x2 : x1;
    v = ((const float4*)src)[bb * 16384 + r4];
  } else {
    v = ((const float4*)out)[idx4];
  }
  const float mean = stats[ch * 2 + 0];
  const float g = gamma[c] * stats[ch * 2 + 1];
  const float bt = beta[c];
  float4 o;
  o.x = (v.x - mean) * g + bt;
  o.y = (v.y - mean) * g + bt;
  o.z = (v.z - mean) * g + bt;
  o.w = (v.w - mean) * g + bt;
  ((float4*)out)[idx4] = o;
}

}  // namespace

extern "C" void kernel_launch(void* const* d_in, const int* in_sizes, int n_in,
                              void* d_out, int out_size, void* d_ws, size_t ws_size,
                              hipStream_t stream) {
  const float* x1 = (const float*)d_in[0];
  const float* x2 = (const float*)d_in[1];
  const float* W = (const float*)d_in[2];
  const float* bias = (const float*)d_in[3];
  const float* gamma = (const float*)d_in[4];
  const float* beta = (const float*)d_in[5];
  float* out = (float*)d_out;
  float* ws = (float*)d_ws;

  float* attn = ws;                    // B*S*S = 1,048,576 floats (4 MB)
  float* psum = ws + 1048576;          // 1024
  float* psq = psum + 1024;            // 1024
  float* stats = psq + 1024;           // 8

  k1_attn<<<dim3(4, 4, 16), 256, 0, stream>>>(x1, x2, attn);
  k2_gemm<<<dim3(4, 4, 32), 256, 0, stream>>>(attn, W, bias, out);
  k3a_partial<<<dim3(256, 4), 256, 0, stream>>>(x1, x2, out, psum, psq);
  k3b_final<<<1, 256, 0, stream>>>(psum, psq, stats);
  k4_bn<<<4096, 256, 0, stream>>>(x1, x2, stats, gamma, beta, out);
}

// Round 6
// 108.726 us; speedup vs baseline: 1.2228x; 1.2228x over previous
//
#include <hip/hip_runtime.h>
#include <hip/hip_bf16.h>
#include <math.h>

namespace {
typedef __attribute__((ext_vector_type(8))) short short8;
typedef __attribute__((ext_vector_type(4))) float f32x4;

constexpr int Bn = 16;
constexpr int Sn = 256;
constexpr int Dn = 256;
constexpr float EPS_ATTN = 1e-6f;
constexpr float EPS_BN = 1e-5f;
constexpr int OUT2 = Bn * 2 * Sn * Dn;  // float offset of second output tensor

__device__ inline uint pack_bf16(float a, float b) {
  uint ua = __float_as_uint(a), ub = __float_as_uint(b);
  ua = (ua + 0x7FFFu + ((ua >> 16) & 1u)) >> 16;  // RNE
  ub = (ub + 0x7FFFu + ((ub >> 16) & 1u)) >> 16;
  return ua | (ub << 16);
}

// ---------------------------------------------------------------------------
// K0: read x1/x2 once -> bf16 copies + exact fp32 row sum-of-squares (norms)
//     + per-block BN partials for channels 0 (x1) and 2 (x2).
// grid (128, 2): 32 rows/block, 8 threads/row (32 floats each).
// ---------------------------------------------------------------------------
__global__ __launch_bounds__(256) void k0_prep(const float* __restrict__ x1,
                                               const float* __restrict__ x2,
                                               ushort* __restrict__ x1b,
                                               ushort* __restrict__ x2b,
                                               float* __restrict__ norms,
                                               float* __restrict__ psum0,
                                               float* __restrict__ psq0) {
  const int tensor = blockIdx.y;
  const float* src = tensor ? x2 : x1;
  ushort* dst = tensor ? x2b : x1b;
  const int t = threadIdx.x;
  const int row = blockIdx.x * 32 + (t >> 3);
  const int seg = (t & 7) * 32;
  const float* p = src + row * Dn + seg;
  ushort* d = dst + row * Dn + seg;
  float s = 0.f, q = 0.f;
#pragma unroll
  for (int k = 0; k < 4; ++k) {
    const float4 a = *(const float4*)(p + k * 8);
    const float4 b = *(const float4*)(p + k * 8 + 4);
    s += a.x + a.y + a.z + a.w + b.x + b.y + b.z + b.w;
    q = fmaf(a.x, a.x, q); q = fmaf(a.y, a.y, q);
    q = fmaf(a.z, a.z, q); q = fmaf(a.w, a.w, q);
    q = fmaf(b.x, b.x, q); q = fmaf(b.y, b.y, q);
    q = fmaf(b.z, b.z, q); q = fmaf(b.w, b.w, q);
    uint4 o;
    o.x = pack_bf16(a.x, a.y);
    o.y = pack_bf16(a.z, a.w);
    o.z = pack_bf16(b.x, b.y);
    o.w = pack_bf16(b.z, b.w);
    *(uint4*)(d + k * 8) = o;
  }
  // row norm: sum q over the 8 lanes of this row (consecutive lanes)
  float qr = q;
  qr += __shfl_down(qr, 1);
  qr += __shfl_down(qr, 2);
  qr += __shfl_down(qr, 4);
  if ((t & 7) == 0) norms[tensor * 4096 + row] = qr;
  // block BN partials
  for (int off = 1; off < 64; off <<= 1) {
    s += __shfl_down(s, off);
    q += __shfl_down(q, off);
  }
  __shared__ float ls[4], lq[4];
  if ((t & 63) == 0) { ls[t >> 6] = s; lq[t >> 6] = q; }
  __syncthreads();
  if (t == 0) {
    psum0[tensor * 128 + blockIdx.x] = ls[0] + ls[1] + ls[2] + ls[3];
    psq0[tensor * 128 + blockIdx.x] = lq[0] + lq[1] + lq[2] + lq[3];
  }
}

// ---------------------------------------------------------------------------
// K1: attn via bf16 MFMA. dist2 = na + nb - 2*dot (norms exact fp32).
// 64x64 tile/block, whole D=256 in LDS (XOR-swizzled). Writes attn in both
// orientations fp32: attn_ji[b][j][i], attn_ij[b][i][j].
// ---------------------------------------------------------------------------
__global__ __launch_bounds__(256) void k1_attn(const ushort* __restrict__ x1b,
                                               const ushort* __restrict__ x2b,
                                               const float* __restrict__ norms,
                                               float* __restrict__ attn_ji,
                                               float* __restrict__ attn_ij) {
  __shared__ __align__(16) ushort a_s[64 * 256];
  __shared__ __align__(16) ushort b_s[64 * 256];
  const int b = blockIdx.z;
  const int ibase = blockIdx.x * 64;
  const int jbase = blockIdx.y * 64;
  const int t = threadIdx.x;

  // stage: 64 rows x 256 bf16 per tensor; thread: row=t>>2, 64 elems
  {
    const int row = t >> 2;
    const int seg = (t & 3) * 64;
    const ushort* g1 = x1b + (b * Sn + ibase + row) * Dn + seg;
    const ushort* g2 = x2b + (b * Sn + jbase + row) * Dn + seg;
    const int swz = (row & 7) << 4;
#pragma unroll
    for (int k = 0; k < 8; ++k) {
      const uint4 va = *(const uint4*)(g1 + k * 8);
      const uint4 vb = *(const uint4*)(g2 + k * 8);
      const int off = (row * 512 + seg * 2 + k * 16) ^ swz;
      *(uint4*)((char*)a_s + off) = va;
      *(uint4*)((char*)b_s + off) = vb;
    }
  }
  __syncthreads();

  const int w = t >> 6;       // wave: i-strip [w*16, w*16+16)
  const int l = t & 63;
  const int lm = l & 15;
  const int lk = l >> 4;

  f32x4 acc[4];
#pragma unroll
  for (int n = 0; n < 4; ++n) acc[n] = (f32x4){0.f, 0.f, 0.f, 0.f};

  const int arow = w * 16 + lm;
  const int abase = arow * 512 + lk * 16;
  const int aswz = (arow & 7) << 4;
#pragma unroll
  for (int d0 = 0; d0 < 256; d0 += 32) {
    const short8 af = *(const short8*)((char*)a_s + ((abase + d0 * 2) ^ aswz));
#pragma unroll
    for (int n = 0; n < 4; ++n) {
      const int brow = n * 16 + lm;
      const int boff = (brow * 512 + lk * 16 + d0 * 2) ^ ((brow & 7) << 4);
      const short8 bf = *(const short8*)((char*)b_s + boff);
      acc[n] = __builtin_amdgcn_mfma_f32_16x16x32_bf16(af, bf, acc[n], 0, 0, 0);
    }
  }

  // epilogue: C element (m = lk*4+reg, col = lm) of each 16x16 frag n
  const int i0 = ibase + w * 16 + lk * 4;
  const float4 nav = *(const float4*)(norms + b * Sn + i0);
  const float* navp = (const float*)&nav;
#pragma unroll
  for (int n = 0; n < 4; ++n) {
    const int j = jbase + n * 16 + lm;
    const float nbv = norms[4096 + b * Sn + j];
    float vals[4];
#pragma unroll
    for (int r = 0; r < 4; ++r) {
      const float dist2 = fmaxf(navp[r] + nbv - 2.f * acc[n][r], 0.f);
      vals[r] = 1.f / (sqrtf(dist2 + EPS_ATTN) + 1.f);
    }
    *(float4*)(attn_ji + (b * Sn + j) * Sn + i0) =
        make_float4(vals[0], vals[1], vals[2], vals[3]);
#pragma unroll
    for (int r = 0; r < 4; ++r) attn_ij[(b * Sn + i0 + r) * Sn + j] = vals[r];
  }
}

// ---------------------------------------------------------------------------
// K2: fp32 GEMM (hedge: attn kept fp32). which=0: out1 ch1 = attn_ji^T-GEMM,
// which=1: out2 ch1. Both A stagings are now direct [k][m] float4.
// Fused per-block sum/sumsq partials for BN channels 1 and 3.
// ---------------------------------------------------------------------------
__global__ __launch_bounds__(256) void k2_gemm(const float* __restrict__ attn_ji,
                                               const float* __restrict__ attn_ij,
                                               const float* __restrict__ Wp,
                                               const float* __restrict__ bias,
                                               float* __restrict__ out,
                                               float* __restrict__ psumA,
                                               float* __restrict__ psqA) {
  __shared__ __align__(16) float a_s[2][32][64];  // [buf][k][m]
  __shared__ __align__(16) float w_s[2][32][64];  // [buf][k][o]
  const int z = blockIdx.z;
  const int b = z >> 1;
  const int which = z & 1;
  const int mbase = blockIdx.x * 64;
  const int obase = blockIdx.y * 64;
  const int t = threadIdx.x;
  const int m0 = (t & 15) * 4;
  const int o0 = (t >> 4) * 4;
  const float* A = (which ? attn_ij : attn_ji) + b * Sn * Sn;

  const int p0 = 2 * t, p1 = 2 * t + 1;
  const int to0 = p0 >> 3, tk0 = (p0 & 7) * 4;  // W transposed staging
  const int to1 = p1 >> 3, tk1 = (p1 & 7) * 4;
  const int ak0 = p0 >> 4, am0 = (p0 & 15) * 4;  // A direct staging
  const int ak1 = p1 >> 4, am1 = (p1 & 15) * 4;

  float4 va0, va1, vw0, vw1;
  auto load_chunk = [&](int k0) {
    va0 = *(const float4*)(A + (k0 + ak0) * Sn + mbase + am0);
    va1 = *(const float4*)(A + (k0 + ak1) * Sn + mbase + am1);
    vw0 = *(const float4*)(Wp + (obase + to0) * Sn + k0 + tk0);
    vw1 = *(const float4*)(Wp + (obase + to1) * Sn + k0 + tk1);
  };
  auto store_chunk = [&](int bf) {
    *(float4*)&a_s[bf][ak0][am0] = va0;
    *(float4*)&a_s[bf][ak1][am1] = va1;
    w_s[bf][tk0 + 0][to0] = vw0.x; w_s[bf][tk0 + 1][to0] = vw0.y;
    w_s[bf][tk0 + 2][to0] = vw0.z; w_s[bf][tk0 + 3][to0] = vw0.w;
    w_s[bf][tk1 + 0][to1] = vw1.x; w_s[bf][tk1 + 1][to1] = vw1.y;
    w_s[bf][tk1 + 2][to1] = vw1.z; w_s[bf][tk1 + 3][to1] = vw1.w;
  };

  float acc[4][4];  // [mm][oo]
#pragma unroll
  for (int a = 0; a < 4; ++a)
#pragma unroll
    for (int c = 0; c < 4; ++c) acc[a][c] = 0.f;

  load_chunk(0);
  store_chunk(0);
  __syncthreads();

  int buf = 0;
  for (int kc = 0; kc < 8; ++kc) {
    if (kc < 7) load_chunk((kc + 1) * 32);
#pragma unroll
    for (int d = 0; d < 32; ++d) {
      const float4 av = *(const float4*)&a_s[buf][d][m0];
      const float4 wv = *(const float4*)&w_s[buf][d][o0];
      acc[0][0] = fmaf(av.x, wv.x, acc[0][0]);
      acc[0][1] = fmaf(av.x, wv.y, acc[0][1]);
      acc[0][2] = fmaf(av.x, wv.z, acc[0][2]);
      acc[0][3] = fmaf(av.x, wv.w, acc[0][3]);
      acc[1][0] = fmaf(av.y, wv.x, acc[1][0]);
      acc[1][1] = fmaf(av.y, wv.y, acc[1][1]);
      acc[1][2] = fmaf(av.y, wv.z, acc[1][2]);
      acc[1][3] = fmaf(av.y, wv.w, acc[1][3]);
      acc[2][0] = fmaf(av.z, wv.x, acc[2][0]);
      acc[2][1] = fmaf(av.z, wv.y, acc[2][1]);
      acc[2][2] = fmaf(av.z, wv.z, acc[2][2]);
      acc[2][3] = fmaf(av.z, wv.w, acc[2][3]);
      acc[3][0] = fmaf(av.w, wv.x, acc[3][0]);
      acc[3][1] = fmaf(av.w, wv.y, acc[3][1]);
      acc[3][2] = fmaf(av.w, wv.z, acc[3][2]);
      acc[3][3] = fmaf(av.w, wv.w, acc[3][3]);
    }
    if (kc < 7) store_chunk(buf ^ 1);
    __syncthreads();
    buf ^= 1;
  }

  const float4 bsv = *(const float4*)(bias + obase + o0);
  float* dst = out + (which ? OUT2 : 0) + ((2 * b + 1) * Sn + mbase) * Dn + obase;
  float s = 0.f, q = 0.f;
#pragma unroll
  for (int mm = 0; mm < 4; ++mm) {
    float4 o;
    o.x = acc[mm][0] + bsv.x;
    o.y = acc[mm][1] + bsv.y;
    o.z = acc[mm][2] + bsv.z;
    o.w = acc[mm][3] + bsv.w;
    s += o.x + o.y + o.z + o.w;
    q = fmaf(o.x, o.x, q); q = fmaf(o.y, o.y, q);
    q = fmaf(o.z, o.z, q); q = fmaf(o.w, o.w, q);
    *(float4*)(dst + (m0 + mm) * Dn + o0) = o;
  }
  for (int off = 1; off < 64; off <<= 1) {
    s += __shfl_down(s, off);
    q += __shfl_down(q, off);
  }
  __shared__ float ls[4], lq[4];
  if ((t & 63) == 0) { ls[t >> 6] = s; lq[t >> 6] = q; }
  __syncthreads();
  if (t == 0) {
    const int idx = which * 256 + b * 16 + blockIdx.y * 4 + blockIdx.x;
    psumA[idx] = ls[0] + ls[1] + ls[2] + ls[3];
    psqA[idx] = lq[0] + lq[1] + lq[2] + lq[3];
  }
}

// ---------------------------------------------------------------------------
// K3: finalize BN stats (1 block; one wave per channel).
// ch = tensor*2 + c. c=0 -> psum0 (128/tensor), c=1 -> psumA (256/tensor).
// ---------------------------------------------------------------------------
__global__ __launch_bounds__(256) void k3_final(const float* __restrict__ psum0,
                                                const float* __restrict__ psq0,
                                                const float* __restrict__ psumA,
                                                const float* __restrict__ psqA,
                                                float* __restrict__ stats) {
  const int t = threadIdx.x;
  const int ch = t >> 6;
  const int l = t & 63;
  const bool att = ch & 1;
  const float* sp = att ? psumA : psum0;
  const float* qp = att ? psqA : psq0;
  const int base = att ? (ch >> 1) * 256 : (ch >> 1) * 128;
  const int n = att ? 256 : 128;
  float s = 0.f, q = 0.f;
  for (int u = l; u < n; u += 64) {
    s += sp[base + u];
    q += qp[base + u];
  }
  for (int off = 1; off < 64; off <<= 1) {
    s += __shfl_down(s, off);
    q += __shfl_down(q, off);
  }
  if (l == 0) {
    const float nf = (float)(Bn * Sn * Dn);
    const float mean = s / nf;
    const float var = q / nf - mean * mean;
    stats[ch * 2 + 0] = mean;
    stats[ch * 2 + 1] = rsqrtf(var + EPS_BN);
  }
}

// ---------------------------------------------------------------------------
// K4: normalize; channel 0 planes from x1/x2, channel 1 planes in-place.
// ---------------------------------------------------------------------------
__global__ __launch_bounds__(256) void k4_bn(const float* __restrict__ x1,
                                             const float* __restrict__ x2,
                                             const float* __restrict__ stats,
                                             const float* __restrict__ gamma,
                                             const float* __restrict__ beta,
                                             float* __restrict__ out) {
  const int idx4 = blockIdx.x * 256 + threadIdx.x;  // f4 units
  const int tensor = idx4 >> 19;
  const int rem = idx4 & 524287;
  const int bb = rem >> 15;
  const int rem2 = rem & 32767;
  const int c = rem2 >> 14;
  const int r4 = rem2 & 16383;
  const int ch = tensor * 2 + c;
  float4 v;
  if (c == 0) {
    const float* src = tensor ? x2 : x1;
    v = ((const float4*)src)[bb * 16384 + r4];
  } else {
    v = ((const float4*)out)[idx4];
  }
  const float mean = stats[ch * 2 + 0];
  const float g = gamma[c] * stats[ch * 2 + 1];
  const float bt = beta[c];
  float4 o;
  o.x = (v.x - mean) * g + bt;
  o.y = (v.y - mean) * g + bt;
  o.z = (v.z - mean) * g + bt;
  o.w = (v.w - mean) * g + bt;
  ((float4*)out)[idx4] = o;
}

}  // namespace

extern "C" void kernel_launch(void* const* d_in, const int* in_sizes, int n_in,
                              void* d_out, int out_size, void* d_ws, size_t ws_size,
                              hipStream_t stream) {
  const float* x1 = (const float*)d_in[0];
  const float* x2 = (const float*)d_in[1];
  const float* W = (const float*)d_in[2];
  const float* bias = (const float*)d_in[3];
  const float* gamma = (const float*)d_in[4];
  const float* beta = (const float*)d_in[5];
  float* out = (float*)d_out;
  float* ws = (float*)d_ws;

  float* attn_ji = ws;                       // 1,048,576 f
  float* attn_ij = ws + 1048576;             // 1,048,576 f
  ushort* x1b = (ushort*)(ws + 2097152);     // 1,048,576 u16 (= 524,288 f)
  ushort* x2b = x1b + 1048576;               // 1,048,576 u16
  float* norms = ws + 2097152 + 1048576;     // 8192 f
  float* psum0 = norms + 8192;               // 256
  float* psq0 = psum0 + 256;                 // 256
  float* psumA = psq0 + 256;                 // 512
  float* psqA = psumA + 512;                 // 512
  float* stats = psqA + 512;                 // 8

  k0_prep<<<dim3(128, 2), 256, 0, stream>>>(x1, x2, x1b, x2b, norms, psum0, psq0);
  k1_attn<<<dim3(4, 4, 16), 256, 0, stream>>>(x1b, x2b, norms, attn_ji, attn_ij);
  k2_gemm<<<dim3(4, 4, 32), 256, 0, stream>>>(attn_ji, attn_ij, W, bias, out, psumA, psqA);
  k3_final<<<1, 256, 0, stream>>>(psum0, psq0, psumA, psqA, stats);
  k4_bn<<<4096, 256, 0, stream>>>(x1, x2, stats, gamma, beta, out);
}

// Round 10
// 107.419 us; speedup vs baseline: 1.2376x; 1.0122x over previous
//
#include <hip/hip_runtime.h>
#include <hip/hip_bf16.h>
#include <math.h>

namespace {
typedef __attribute__((ext_vector_type(8))) short short8;
typedef __attribute__((ext_vector_type(4))) float f32x4;

constexpr int Bn = 16;
constexpr int Sn = 256;
constexpr int Dn = 256;
constexpr float EPS_ATTN = 1e-6f;
constexpr float EPS_BN = 1e-5f;
constexpr int OUT2 = Bn * 2 * Sn * Dn;  // float offset of second output tensor

__device__ inline uint pack_bf16(float a, float b) {
  uint ua = __float_as_uint(a), ub = __float_as_uint(b);
  ua = (ua + 0x7FFFu + ((ua >> 16) & 1u)) >> 16;  // RNE
  ub = (ub + 0x7FFFu + ((ub >> 16) & 1u)) >> 16;
  return ua | (ub << 16);
}

// ---------------------------------------------------------------------------
// K1: attn via bf16 MFMA, fp32 sources read directly (K0 deleted).
// Per block: stage 64x256 fp32 -> bf16 LDS (XOR-swizzled), row norms -> LDS,
// edge blocks emit BN partials for ch0 (x1) / ch2 (x2).
// dist2 = na + nb - 2*dot; writes attn both orientations fp32.
// ---------------------------------------------------------------------------
__global__ __launch_bounds__(256) void k1_attn(const float* __restrict__ x1,
                                               const float* __restrict__ x2,
                                               float* __restrict__ attn_ji,
                                               float* __restrict__ attn_ij,
                                               float* __restrict__ psum0,
                                               float* __restrict__ psq0) {
  __shared__ __align__(16) ushort a_s[64 * 256];  // 32 KB
  __shared__ __align__(16) ushort b_s[64 * 256];  // 32 KB
  __shared__ float norm_a[64], norm_b[64];
  __shared__ float lsA[4], lqA[4], lsB[4], lqB[4];
  const int b = blockIdx.z;
  const int ibase = blockIdx.x * 64;
  const int jbase = blockIdx.y * 64;
  const int t = threadIdx.x;
  const int w = t >> 6;  // wave id
  const int l = t & 63;

  // stage: thread -> row (t>>2), 64-float segment ((t&3)*64); fp32->bf16
  const int row = t >> 2;
  const int seg = (t & 3) * 64;
  const float* g1 = x1 + (b * Sn + ibase + row) * Dn + seg;
  const float* g2 = x2 + (b * Sn + jbase + row) * Dn + seg;
  const int swz = (row & 7) << 4;
  float s1 = 0.f, q1 = 0.f, s2 = 0.f, q2 = 0.f;
#pragma unroll
  for (int c = 0; c < 8; ++c) {
    const float4 a0 = *(const float4*)(g1 + c * 8);
    const float4 a1 = *(const float4*)(g1 + c * 8 + 4);
    const float4 b0 = *(const float4*)(g2 + c * 8);
    const float4 b1 = *(const float4*)(g2 + c * 8 + 4);
    s1 += a0.x + a0.y + a0.z + a0.w + a1.x + a1.y + a1.z + a1.w;
    q1 = fmaf(a0.x, a0.x, q1); q1 = fmaf(a0.y, a0.y, q1);
    q1 = fmaf(a0.z, a0.z, q1); q1 = fmaf(a0.w, a0.w, q1);
    q1 = fmaf(a1.x, a1.x, q1); q1 = fmaf(a1.y, a1.y, q1);
    q1 = fmaf(a1.z, a1.z, q1); q1 = fmaf(a1.w, a1.w, q1);
    s2 += b0.x + b0.y + b0.z + b0.w + b1.x + b1.y + b1.z + b1.w;
    q2 = fmaf(b0.x, b0.x, q2); q2 = fmaf(b0.y, b0.y, q2);
    q2 = fmaf(b0.z, b0.z, q2); q2 = fmaf(b0.w, b0.w, q2);
    q2 = fmaf(b1.x, b1.x, q2); q2 = fmaf(b1.y, b1.y, q2);
    q2 = fmaf(b1.z, b1.z, q2); q2 = fmaf(b1.w, b1.w, q2);
    const uint4 ua = make_uint4(pack_bf16(a0.x, a0.y), pack_bf16(a0.z, a0.w),
                                pack_bf16(a1.x, a1.y), pack_bf16(a1.z, a1.w));
    const uint4 ub = make_uint4(pack_bf16(b0.x, b0.y), pack_bf16(b0.z, b0.w),
                                pack_bf16(b1.x, b1.y), pack_bf16(b1.z, b1.w));
    const int off = (row * 512 + seg * 2 + c * 16) ^ swz;
    *(uint4*)((char*)a_s + off) = ua;
    *(uint4*)((char*)b_s + off) = ub;
  }

  // row norms: reduce q over the 4 consecutive lanes sharing a row
  {
    float qr = q1;
    qr += __shfl_down(qr, 1);
    qr += __shfl_down(qr, 2);
    if ((t & 3) == 0) norm_a[row] = qr;
    float qs = q2;
    qs += __shfl_down(qs, 1);
    qs += __shfl_down(qs, 2);
    if ((t & 3) == 0) norm_b[row] = qs;
  }

  // BN partials for ch0/ch2: only edge blocks (single writer per slot)
  if (jbase == 0) {
    float s = s1, q = q1;
    for (int off = 1; off < 64; off <<= 1) {
      s += __shfl_down(s, off);
      q += __shfl_down(q, off);
    }
    if (l == 0) { lsA[w] = s; lqA[w] = q; }
  }
  if (ibase == 0) {
    float s = s2, q = q2;
    for (int off = 1; off < 64; off <<= 1) {
      s += __shfl_down(s, off);
      q += __shfl_down(q, off);
    }
    if (l == 0) { lsB[w] = s; lqB[w] = q; }
  }
  __syncthreads();
  if (t == 0) {
    if (jbase == 0) {
      psum0[b * 4 + blockIdx.x] = lsA[0] + lsA[1] + lsA[2] + lsA[3];
      psq0[b * 4 + blockIdx.x] = lqA[0] + lqA[1] + lqA[2] + lqA[3];
    }
    if (ibase == 0) {
      psum0[64 + b * 4 + blockIdx.y] = lsB[0] + lsB[1] + lsB[2] + lsB[3];
      psq0[64 + b * 4 + blockIdx.y] = lqB[0] + lqB[1] + lqB[2] + lqB[3];
    }
  }

  // MFMA: wave w owns i-strip [w*16, w*16+16)
  const int lm = l & 15;
  const int lk = l >> 4;
  f32x4 acc[4];
#pragma unroll
  for (int n = 0; n < 4; ++n) acc[n] = (f32x4){0.f, 0.f, 0.f, 0.f};

  const int arow = w * 16 + lm;
  const int abase = arow * 512 + lk * 16;
  const int aswz = (arow & 7) << 4;
#pragma unroll
  for (int d0 = 0; d0 < 256; d0 += 32) {
    const short8 af = *(const short8*)((char*)a_s + ((abase + d0 * 2) ^ aswz));
#pragma unroll
    for (int n = 0; n < 4; ++n) {
      const int brow = n * 16 + lm;
      const int boff = (brow * 512 + lk * 16 + d0 * 2) ^ ((brow & 7) << 4);
      const short8 bf = *(const short8*)((char*)b_s + boff);
      acc[n] = __builtin_amdgcn_mfma_f32_16x16x32_bf16(af, bf, acc[n], 0, 0, 0);
    }
  }

  // epilogue: C element (m = lk*4+reg, col = lm) of each 16x16 frag n
  const int i0l = w * 16 + lk * 4;
  const int i0 = ibase + i0l;
  const float navp[4] = {norm_a[i0l], norm_a[i0l + 1], norm_a[i0l + 2],
                         norm_a[i0l + 3]};
#pragma unroll
  for (int n = 0; n < 4; ++n) {
    const int j = jbase + n * 16 + lm;
    const float nbv = norm_b[n * 16 + lm];
    float vals[4];
#pragma unroll
    for (int r = 0; r < 4; ++r) {
      const float dist2 = fmaxf(navp[r] + nbv - 2.f * acc[n][r], 0.f);
      vals[r] = 1.f / (sqrtf(dist2 + EPS_ATTN) + 1.f);
    }
    *(float4*)(attn_ji + (b * Sn + j) * Sn + i0) =
        make_float4(vals[0], vals[1], vals[2], vals[3]);
#pragma unroll
    for (int r = 0; r < 4; ++r) attn_ij[(b * Sn + i0 + r) * Sn + j] = vals[r];
  }
}

// ---------------------------------------------------------------------------
// K2: fp32 GEMM. which=0: out1 ch1 plane; which=1: out2 ch1 plane.
// Fused per-block sum/sumsq partials for BN channels 1 and 3. (unchanged)
// ---------------------------------------------------------------------------
__global__ __launch_bounds__(256) void k2_gemm(const float* __restrict__ attn_ji,
                                               const float* __restrict__ attn_ij,
                                               const float* __restrict__ Wp,
                                               const float* __restrict__ bias,
                                               float* __restrict__ out,
                                               float* __restrict__ psumA,
                                               float* __restrict__ psqA) {
  __shared__ __align__(16) float a_s[2][32][64];  // [buf][k][m]
  __shared__ __align__(16) float w_s[2][32][64];  // [buf][k][o]
  const int z = blockIdx.z;
  const int b = z >> 1;
  const int which = z & 1;
  const int mbase = blockIdx.x * 64;
  const int obase = blockIdx.y * 64;
  const int t = threadIdx.x;
  const int m0 = (t & 15) * 4;
  const int o0 = (t >> 4) * 4;
  const float* A = (which ? attn_ij : attn_ji) + b * Sn * Sn;

  const int p0 = 2 * t, p1 = 2 * t + 1;
  const int to0 = p0 >> 3, tk0 = (p0 & 7) * 4;  // W transposed staging
  const int to1 = p1 >> 3, tk1 = (p1 & 7) * 4;
  const int ak0 = p0 >> 4, am0 = (p0 & 15) * 4;  // A direct staging
  const int ak1 = p1 >> 4, am1 = (p1 & 15) * 4;

  float4 va0, va1, vw0, vw1;
  auto load_chunk = [&](int k0) {
    va0 = *(const float4*)(A + (k0 + ak0) * Sn + mbase + am0);
    va1 = *(const float4*)(A + (k0 + ak1) * Sn + mbase + am1);
    vw0 = *(const float4*)(Wp + (obase + to0) * Sn + k0 + tk0);
    vw1 = *(const float4*)(Wp + (obase + to1) * Sn + k0 + tk1);
  };
  auto store_chunk = [&](int bf) {
    *(float4*)&a_s[bf][ak0][am0] = va0;
    *(float4*)&a_s[bf][ak1][am1] = va1;
    w_s[bf][tk0 + 0][to0] = vw0.x; w_s[bf][tk0 + 1][to0] = vw0.y;
    w_s[bf][tk0 + 2][to0] = vw0.z; w_s[bf][tk0 + 3][to0] = vw0.w;
    w_s[bf][tk1 + 0][to1] = vw1.x; w_s[bf][tk1 + 1][to1] = vw1.y;
    w_s[bf][tk1 + 2][to1] = vw1.z; w_s[bf][tk1 + 3][to1] = vw1.w;
  };

  float acc[4][4];  // [mm][oo]
#pragma unroll
  for (int a = 0; a < 4; ++a)
#pragma unroll
    for (int c = 0; c < 4; ++c) acc[a][c] = 0.f;

  load_chunk(0);
  store_chunk(0);
  __syncthreads();

  int buf = 0;
  for (int kc = 0; kc < 8; ++kc) {
    if (kc < 7) load_chunk((kc + 1) * 32);
#pragma unroll
    for (int d = 0; d < 32; ++d) {
      const float4 av = *(const float4*)&a_s[buf][d][m0];
      const float4 wv = *(const float4*)&w_s[buf][d][o0];
      acc[0][0] = fmaf(av.x, wv.x, acc[0][0]);
      acc[0][1] = fmaf(av.x, wv.y, acc[0][1]);
      acc[0][2] = fmaf(av.x, wv.z, acc[0][2]);
      acc[0][3] = fmaf(av.x, wv.w, acc[0][3]);
      acc[1][0] = fmaf(av.y, wv.x, acc[1][0]);
      acc[1][1] = fmaf(av.y, wv.y, acc[1][1]);
      acc[1][2] = fmaf(av.y, wv.z, acc[1][2]);
      acc[1][3] = fmaf(av.y, wv.w, acc[1][3]);
      acc[2][0] = fmaf(av.z, wv.x, acc[2][0]);
      acc[2][1] = fmaf(av.z, wv.y, acc[2][1]);
      acc[2][2] = fmaf(av.z, wv.z, acc[2][2]);
      acc[2][3] = fmaf(av.z, wv.w, acc[2][3]);
      acc[3][0] = fmaf(av.w, wv.x, acc[3][0]);
      acc[3][1] = fmaf(av.w, wv.y, acc[3][1]);
      acc[3][2] = fmaf(av.w, wv.z, acc[3][2]);
      acc[3][3] = fmaf(av.w, wv.w, acc[3][3]);
    }
    if (kc < 7) store_chunk(buf ^ 1);
    __syncthreads();
    buf ^= 1;
  }

  const float4 bsv = *(const float4*)(bias + obase + o0);
  float* dst = out + (which ? OUT2 : 0) + ((2 * b + 1) * Sn + mbase) * Dn + obase;
  float s = 0.f, q = 0.f;
#pragma unroll
  for (int mm = 0; mm < 4; ++mm) {
    float4 o;
    o.x = acc[mm][0] + bsv.x;
    o.y = acc[mm][1] + bsv.y;
    o.z = acc[mm][2] + bsv.z;
    o.w = acc[mm][3] + bsv.w;
    s += o.x + o.y + o.z + o.w;
    q = fmaf(o.x, o.x, q); q = fmaf(o.y, o.y, q);
    q = fmaf(o.z, o.z, q); q = fmaf(o.w, o.w, q);
    *(float4*)(dst + (m0 + mm) * Dn + o0) = o;
  }
  for (int off = 1; off < 64; off <<= 1) {
    s += __shfl_down(s, off);
    q += __shfl_down(q, off);
  }
  __shared__ float ls[4], lq[4];
  if ((t & 63) == 0) { ls[t >> 6] = s; lq[t >> 6] = q; }
  __syncthreads();
  if (t == 0) {
    const int idx = which * 256 + b * 16 + blockIdx.y * 4 + blockIdx.x;
    psumA[idx] = ls[0] + ls[1] + ls[2] + ls[3];
    psqA[idx] = lq[0] + lq[1] + lq[2] + lq[3];
  }
}

// ---------------------------------------------------------------------------
// K4: fused stats-finalize + normalize (K3 deleted). Each block recomputes
// the 4 channel stats from partials (one wave per channel, deterministic),
// then normalizes 4 float4 per thread. grid 1024.
// ---------------------------------------------------------------------------
__global__ __launch_bounds__(256) void k4_bn(const float* __restrict__ x1,
                                             const float* __restrict__ x2,
                                             const float* __restrict__ psum0,
                                             const float* __restrict__ psq0,
                                             const float* __restrict__ psumA,
                                             const float* __restrict__ psqA,
                                             const float* __restrict__ gamma,
                                             const float* __restrict__ beta,
                                             float* __restrict__ out) {
  __shared__ float st[8];  // mean, inv_std per channel
  const int t = threadIdx.x;
  const int wv = t >> 6;
  const int l = t & 63;
  {
    const bool att = wv & 1;
    const float* sp = att ? psumA : psum0;
    const float* qp = att ? psqA : psq0;
    const int base = att ? (wv >> 1) * 256 : (wv >> 1) * 64;
    const int n = att ? 256 : 64;
    float s = 0.f, q = 0.f;
    for (int u = l; u < n; u += 64) {
      s += sp[base + u];
      q += qp[base + u];
    }
    for (int off = 1; off < 64; off <<= 1) {
      s += __shfl_down(s, off);
      q += __shfl_down(q, off);
    }
    if (l == 0) {
      const float nf = (float)(Bn * Sn * Dn);
      const float mean = s / nf;
      const float var = q / nf - mean * mean;
      st[wv * 2 + 0] = mean;
      st[wv * 2 + 1] = rsqrtf(var + EPS_BN);
    }
  }
  __syncthreads();

#pragma unroll
  for (int u = 0; u < 4; ++u) {
    const int idx4 = blockIdx.x * 1024 + u * 256 + t;  // f4 units
    const int tensor = idx4 >> 19;
    const int rem = idx4 & 524287;
    const int bb = rem >> 15;
    const int rem2 = rem & 32767;
    const int c = rem2 >> 14;
    const int r4 = rem2 & 16383;
    const int ch = tensor * 2 + c;
    float4 v;
    if (c == 0) {
      const float* src = tensor ? x2 : x1;
      v = ((const float4*)src)[bb * 16384 + r4];
    } else {
      v = ((const float4*)out)[idx4];
    }
    const float mean = st[ch * 2 + 0];
    const float g = gamma[c] * st[ch * 2 + 1];
    const float bt = beta[c];
    float4 o;
    o.x = (v.x - mean) * g + bt;
    o.y = (v.y - mean) * g + bt;
    o.z = (v.z - mean) * g + bt;
    o.w = (v.w - mean) * g + bt;
    ((float4*)out)[idx4] = o;
  }
}

}  // namespace

extern "C" void kernel_launch(void* const* d_in, const int* in_sizes, int n_in,
                              void* d_out, int out_size, void* d_ws, size_t ws_size,
                              hipStream_t stream) {
  const float* x1 = (const float*)d_in[0];
  const float* x2 = (const float*)d_in[1];
  const float* W = (const float*)d_in[2];
  const float* bias = (const float*)d_in[3];
  const float* gamma = (const float*)d_in[4];
  const float* beta = (const float*)d_in[5];
  float* out = (float*)d_out;
  float* ws = (float*)d_ws;

  float* attn_ji = ws;           // 1,048,576 f
  float* attn_ij = ws + 1048576; // 1,048,576 f
  float* psum0 = ws + 2097152;   // 128 (64 per tensor)
  float* psq0 = psum0 + 128;     // 128
  float* psumA = psq0 + 128;     // 512 (256 per which)
  float* psqA = psumA + 512;     // 512

  k1_attn<<<dim3(4, 4, 16), 256, 0, stream>>>(x1, x2, attn_ji, attn_ij, psum0, psq0);
  k2_gemm<<<dim3(4, 4, 32), 256, 0, stream>>>(attn_ji, attn_ij, W, bias, out, psumA, psqA);
  k4_bn<<<1024, 256, 0, stream>>>(x1, x2, psum0, psq0, psumA, psqA, gamma, beta, out);
}